// Round 5
// baseline (350.098 us; speedup 1.0000x reference)
//
#include <hip/hip_runtime.h>
#include <hip/hip_fp16.h>
#include <math.h>

#define IN_D 64
#define HID_D 128
#define OUT_D 64

typedef _Float16 half8 __attribute__((ext_vector_type(8)));
typedef float f32x4 __attribute__((ext_vector_type(4)));

// ---------------------------------------------------------------------------
// Decode edge_index (robust to int32 or int64 storage) + int in-degree histogram
__global__ void k_decode(const unsigned int* __restrict__ raw, int E,
                         int* __restrict__ src, int* __restrict__ dst,
                         int* __restrict__ deg) {
    __shared__ int is64;
    if (threadIdx.x == 0) {
        int f = 1;
        for (int i = 1; i < 64; i += 2) f &= (raw[i] == 0u);
        is64 = f;
    }
    __syncthreads();
    int e = blockIdx.x * blockDim.x + threadIdx.x;
    if (e >= E) return;
    int s, d;
    if (is64) {
        s = (int)raw[2 * (size_t)e];
        d = (int)raw[2 * ((size_t)E + e)];
    } else {
        s = (int)raw[e];
        d = (int)raw[E + e];
    }
    src[e] = s;
    dst[e] = d;
    atomicAdd(&deg[d], 1);
}

// ---------------------------------------------------------------------------
// Exclusive scan of deg -> row_ptr
__global__ void k_scanA(const int* __restrict__ deg, int* __restrict__ part,
                        int* __restrict__ blksum, int N) {
    int i = blockIdx.x * 256 + threadIdx.x;
    int v = (i < N) ? deg[i] : 0;
    int lane = threadIdx.x & 63, w = threadIdx.x >> 6;
    for (int off = 1; off < 64; off <<= 1) {
        int n = __shfl_up(v, off);
        if (lane >= off) v += n;
    }
    __shared__ int wsum[4];
    if (lane == 63) wsum[w] = v;
    __syncthreads();
    for (int k = 0; k < w; ++k) v += wsum[k];
    if (i < N) part[i] = v;
    if (threadIdx.x == 255) blksum[blockIdx.x] = v;
}

__global__ void k_scanB(int* __restrict__ blksum, int nb) {
    int t = threadIdx.x;  // 512 threads, nb <= 512
    int v = (t < nb) ? blksum[t] : 0;
    int orig = v;
    int lane = t & 63, w = t >> 6;
    for (int off = 1; off < 64; off <<= 1) {
        int n = __shfl_up(v, off);
        if (lane >= off) v += n;
    }
    __shared__ int wsum[8];
    if (lane == 63) wsum[w] = v;
    __syncthreads();
    for (int k = 0; k < w; ++k) v += wsum[k];
    if (t < nb) blksum[t] = v - orig;
}

// row_ptr, dinv, and per-bucket base cursors (bucket = dst>>9)
__global__ void k_scanC(const int* __restrict__ deg, const int* __restrict__ part,
                        const int* __restrict__ blksum, int* __restrict__ row_ptr,
                        int* __restrict__ bcur, float* __restrict__ dinv,
                        int N, int E) {
    int i = blockIdx.x * 256 + threadIdx.x;
    if (i == 0) row_ptr[N] = E;
    if (i >= N) return;
    int start = part[i] - deg[i] + blksum[blockIdx.x];
    row_ptr[i] = start;
    if ((i & 511) == 0) bcur[i >> 9] = start;
    dinv[i] = rsqrtf((float)deg[i] + 1.0f);  // +1 = self loop
}

// ---------------------------------------------------------------------------
// Phase A: partition edges into coarse dst-buckets (512 nodes each).
// 8 B records written in contiguous runs -> near-full-line writebacks.
#define CHUNK 2048
__global__ __launch_bounds__(256) void k_part(const int* __restrict__ src,
                                              const int* __restrict__ dst,
                                              int* __restrict__ bcur,
                                              int2* __restrict__ pairs, int E) {
    __shared__ int hist[256];
    __shared__ int base[256];
    __shared__ int cnt[256];
    for (int i = threadIdx.x; i < 256; i += 256) { hist[i] = 0; cnt[i] = 0; }
    __syncthreads();
    int e0 = blockIdx.x * CHUNK;
    int s[8], d[8], b[8];
#pragma unroll
    for (int i = 0; i < 8; ++i) {
        int e = e0 + threadIdx.x + i * 256;
        if (e < E) {
            s[i] = src[e]; d[i] = dst[e]; b[i] = d[i] >> 9;
            atomicAdd(&hist[b[i]], 1);
        } else b[i] = -1;
    }
    __syncthreads();
    if (hist[threadIdx.x] > 0)
        base[threadIdx.x] = atomicAdd(&bcur[threadIdx.x], hist[threadIdx.x]);
    __syncthreads();
#pragma unroll
    for (int i = 0; i < 8; ++i) {
        if (b[i] >= 0) {
            int pos = base[b[i]] + atomicAdd(&cnt[b[i]], 1);
            pairs[pos] = make_int2(s[i], d[i]);
        }
    }
}

// Phase B: one block per bucket; LDS cursors; writes confined to one
// 20 KB CSR region per block (single XCD -> full-line writebacks).
__global__ __launch_bounds__(256) void k_place2(const int2* __restrict__ pairs,
                                                const int* __restrict__ row_ptr,
                                                int* __restrict__ csr_src, int N) {
    __shared__ int cur[512];
    int b = blockIdx.x;
    int n0 = b << 9;
    int n1 = n0 + 512; if (n1 > N) n1 = N;
    for (int j = threadIdx.x; j < n1 - n0; j += 256) cur[j] = row_ptr[n0 + j];
    __syncthreads();
    int beg = row_ptr[n0], end = row_ptr[n1];
    for (int i = beg + threadIdx.x; i < end; i += 256) {
        int2 r = pairs[i];
        int pos = atomicAdd(&cur[r.y - n0], 1);
        csr_src[pos] = r.x;
    }
}

// ---------------------------------------------------------------------------
// xs panel layout: xs_p[panel][node][16 cols], panel = col>>4. fp16 pre-scaled.
__global__ void k_xconv(const float* __restrict__ x, const float* __restrict__ dinv,
                        __half* __restrict__ xs_p, int N) {
    int idx = blockIdx.x * blockDim.x + threadIdx.x;
    if (idx >= N * 32) return;
    int i = idx >> 5, c2 = idx & 31;
    int col = c2 * 2;
    int panel = col >> 4, cw = col & 15;
    float di = dinv[i];
    float2 v = *(const float2*)&x[(size_t)i * 64 + col];
    *(__half2*)&xs_p[(size_t)panel * N * 16 + (size_t)i * 16 + cw] =
        __floats2half2_rn(v.x * di, v.y * di);
}

// ---------------------------------------------------------------------------
// Pre-pack W1 (A-operand layout) and W2 (B-operand layout) into MFMA fragment order.
__global__ void k_wconv(const float* __restrict__ W1, const float* __restrict__ W2,
                        __half* __restrict__ w1f, __half* __restrict__ w2f) {
    int t = blockIdx.x * 256 + threadIdx.x;  // 0..2047
    if (t >= 2048) return;
    int which = t >> 10;
    int fl = t & 1023;
    int f = fl >> 6, l = fl & 63;
    int q = l >> 4, n16 = l & 15;
    if (which == 0) {
        int nt = f >> 1, kc = f & 1;
        int n = nt * 16 + n16;
        int k0 = kc * 32 + q * 8;
        for (int j = 0; j < 8; ++j)
            w1f[(size_t)fl * 8 + j] = __float2half(W1[(k0 + j) * 128 + n]);
    } else {
        int nt = f >> 2, kc = f & 3;
        int n = nt * 16 + n16;
        int k0 = kc * 32 + q * 8;
        for (int j = 0; j < 8; ++j)
            w2f[(size_t)fl * 8 + j] = __float2half(W2[(k0 + j) * 64 + n]);
    }
}

// ---------------------------------------------------------------------------
// Panel gather, layer 1: agg[node][panel*16+..] = dinv * (self + sum nbrs) (fp16)
// panel = blockIdx%4 (XCD-affine: each XCD's L2 caches one 3.2 MB panel).
// Wave: 2 nodes x 4 neighbor-slots x 8 half2 columns.
__global__ void k_gather1(const __half* __restrict__ xs_p, const float* __restrict__ dinv,
                          const int* __restrict__ row_ptr, const int* __restrict__ csr,
                          __half* __restrict__ agg, int N) {
    int panel = blockIdx.x & 3;
    int l = threadIdx.x & 63;
    int nl = l >> 5, slot = (l >> 3) & 3, cp = l & 7;
    int node = (blockIdx.x >> 2) * 8 + (threadIdx.x >> 6) * 2 + nl;
    if (node >= N) return;
    const __half* tab = xs_p + (size_t)panel * N * 16;
    int beg = row_ptr[node], end = row_ptr[node + 1];
    float ax = 0.f, ay = 0.f;
    for (int k = beg + slot; k < end; k += 4) {
        int s = csr[k];
        float2 f = __half22float2(*(const __half2*)&tab[(size_t)s * 16 + cp * 2]);
        ax += f.x; ay += f.y;
    }
    ax += __shfl_xor(ax, 8);  ay += __shfl_xor(ay, 8);
    ax += __shfl_xor(ax, 16); ay += __shfl_xor(ay, 16);
    if (slot == 0) {
        float2 fs = __half22float2(*(const __half2*)&tab[(size_t)node * 16 + cp * 2]);
        float di = dinv[node];
        *(__half2*)&agg[(size_t)node * 64 + panel * 16 + cp * 2] =
            __floats2half2_rn((ax + fs.x) * di, (ay + fs.y) * di);
    }
}

// Panel gather, layer 2, fused with +b2/relu/Wc partial dots -> per-panel partials.
__global__ void k_gather2(const __half* __restrict__ ts_p, const float* __restrict__ dinv,
                          const int* __restrict__ row_ptr, const int* __restrict__ csr,
                          const float* __restrict__ b2, const float* __restrict__ Wc,
                          float* __restrict__ p0p, float* __restrict__ p1p, int N) {
    int panel = blockIdx.x & 3;
    int l = threadIdx.x & 63;
    int nl = l >> 5, slot = (l >> 3) & 3, cp = l & 7;
    int node = (blockIdx.x >> 2) * 8 + (threadIdx.x >> 6) * 2 + nl;
    if (node >= N) return;
    const __half* tab = ts_p + (size_t)panel * N * 16;
    int beg = row_ptr[node], end = row_ptr[node + 1];
    float ax = 0.f, ay = 0.f;
    for (int k = beg + slot; k < end; k += 4) {
        int s = csr[k];
        float2 f = __half22float2(*(const __half2*)&tab[(size_t)s * 16 + cp * 2]);
        ax += f.x; ay += f.y;
    }
    ax += __shfl_xor(ax, 8);  ay += __shfl_xor(ay, 8);
    ax += __shfl_xor(ax, 16); ay += __shfl_xor(ay, 16);
    // all lanes now hold the slot-reduced sums; compute panel-partial scores
    float2 fs = __half22float2(*(const __half2*)&tab[(size_t)node * 16 + cp * 2]);
    float di = dinv[node];
    int col = panel * 16 + cp * 2;
    float2 bb = *(const float2*)&b2[col];
    float vx = fmaxf((ax + fs.x) * di + bb.x, 0.f);
    float vy = fmaxf((ay + fs.y) * di + bb.y, 0.f);
    float2 w0 = *(const float2*)&Wc[col];
    float2 w1 = *(const float2*)&Wc[64 + col];
    float p0 = vx * w0.x + vy * w0.y;
    float p1 = vx * w1.x + vy * w1.y;
    p0 += __shfl_xor(p0, 1); p1 += __shfl_xor(p1, 1);
    p0 += __shfl_xor(p0, 2); p1 += __shfl_xor(p1, 2);
    p0 += __shfl_xor(p0, 4); p1 += __shfl_xor(p1, 4);
    if ((l & 31) == 0) {
        p0p[(size_t)panel * N + node] = p0;
        p1p[(size_t)panel * N + node] = p1;
    }
}

// Sum the 4 per-panel partials -> s0, s1
__global__ void k_sfin(const float* __restrict__ p0p, const float* __restrict__ p1p,
                       float* __restrict__ s0, float* __restrict__ s1, int N) {
    int i = blockIdx.x * blockDim.x + threadIdx.x;
    if (i >= N) return;
    s0[i] = p0p[i] + p0p[N + i] + p0p[2 * (size_t)N + i] + p0p[3 * (size_t)N + i];
    s1[i] = p1p[i] + p1p[N + i] + p1p[2 * (size_t)N + i] + p1p[3 * (size_t)N + i];
}

// ---------------------------------------------------------------------------
// MFMA fused MLP: ts_p = fp16( dinv * ( relu(agg @ W1 + b1) @ W2 ) ), panel output
__global__ __launch_bounds__(256) void k_mlp_mfma(const __half* __restrict__ agg_h,
                                                  const __half* __restrict__ w1f,
                                                  const __half* __restrict__ w2f,
                                                  const float* __restrict__ b1,
                                                  const float* __restrict__ dinv,
                                                  __half* __restrict__ ts_p, int N) {
    __shared__ __align__(16) __half w1l[8192];
    __shared__ __align__(16) __half w2l[8192];
    {
        const float4* sA = (const float4*)w1f;
        const float4* sB = (const float4*)w2f;
        float4* dA = (float4*)w1l;
        float4* dB = (float4*)w2l;
        for (int i = threadIdx.x; i < 1024; i += 256) { dA[i] = sA[i]; dB[i] = sB[i]; }
    }
    __syncthreads();

    int wv = threadIdx.x >> 6, l = threadIdx.x & 63;
    int m0 = blockIdx.x * 64 + wv * 16;
    if (m0 >= N) return;
    int q = l >> 4, ml = l & 15;
    int rowA = m0 + ml; if (rowA >= N) rowA = N - 1;

    half8 bfr0 = *(const half8*)&agg_h[(size_t)rowA * 64 + q * 8];
    half8 bfr1 = *(const half8*)&agg_h[(size_t)rowA * 64 + 32 + q * 8];

    int pk[8][2];
#pragma unroll
    for (int nt = 0; nt < 8; ++nt) {
        float4 bb = *(const float4*)&b1[nt * 16 + q * 4];
        f32x4 cacc; cacc[0] = bb.x; cacc[1] = bb.y; cacc[2] = bb.z; cacc[3] = bb.w;
        half8 a0 = *(const half8*)&w1l[(nt * 2 + 0) * 512 + l * 8];
        cacc = __builtin_amdgcn_mfma_f32_16x16x32_f16(a0, bfr0, cacc, 0, 0, 0);
        half8 a1 = *(const half8*)&w1l[(nt * 2 + 1) * 512 + l * 8];
        cacc = __builtin_amdgcn_mfma_f32_16x16x32_f16(a1, bfr1, cacc, 0, 0, 0);
        union { __half2 h; int i; } u0, u1;
        u0.h = __floats2half2_rn(fmaxf(cacc[0], 0.f), fmaxf(cacc[1], 0.f));
        u1.h = __floats2half2_rn(fmaxf(cacc[2], 0.f), fmaxf(cacc[3], 0.f));
        pk[nt][0] = u0.i;
        pk[nt][1] = u1.i;
    }

    int src0 = ml + 16 * ((2 * q) & 3);
    int src1 = ml + 16 * ((2 * q + 1) & 3);
    bool hi = (q >= 2);
    half8 afr[4];
#pragma unroll
    for (int kc = 0; kc < 4; ++kc) {
        int t0 = 2 * kc, t1 = 2 * kc + 1;
        int d0a = __shfl(pk[t0][0], src0), d0b = __shfl(pk[t1][0], src0);
        int d1a = __shfl(pk[t0][1], src0), d1b = __shfl(pk[t1][1], src0);
        int d2a = __shfl(pk[t0][0], src1), d2b = __shfl(pk[t1][0], src1);
        int d3a = __shfl(pk[t0][1], src1), d3b = __shfl(pk[t1][1], src1);
        union { int d[4]; half8 h; } u;
        u.d[0] = hi ? d0b : d0a;
        u.d[1] = hi ? d1b : d1a;
        u.d[2] = hi ? d2b : d2a;
        u.d[3] = hi ? d3b : d3a;
        afr[kc] = u.h;
    }

    float dl = dinv[rowA];
    float dv[4];
#pragma unroll
    for (int r = 0; r < 4; ++r) dv[r] = __shfl(dl, q * 4 + r);

    size_t N16 = (size_t)N * 16;
#pragma unroll
    for (int nt2 = 0; nt2 < 4; ++nt2) {
        f32x4 cacc; cacc[0] = 0.f; cacc[1] = 0.f; cacc[2] = 0.f; cacc[3] = 0.f;
#pragma unroll
        for (int kc = 0; kc < 4; ++kc) {
            half8 b = *(const half8*)&w2l[(nt2 * 4 + kc) * 512 + l * 8];
            cacc = __builtin_amdgcn_mfma_f32_16x16x32_f16(afr[kc], b, cacc, 0, 0, 0);
        }
#pragma unroll
        for (int r = 0; r < 4; ++r) {
            int node = m0 + q * 4 + r;
            if (node < N)
                ts_p[(size_t)nt2 * N16 + (size_t)node * 16 + ml] =
                    __float2half(cacc[r] * dv[r]);
        }
    }
}

__global__ void k_edge(const int* __restrict__ src, const int* __restrict__ dst,
                       const float* __restrict__ s0, const float* __restrict__ s1,
                       const float* __restrict__ bc, float* __restrict__ out, int E) {
    int e = blockIdx.x * blockDim.x + threadIdx.x;
    if (e >= E) return;
    float z = s0[src[e]] + s1[dst[e]] + bc[0];
    out[e] = 1.0f / (1.0f + expf(-z));
}

// ---------------------------------------------------------------------------
extern "C" void kernel_launch(void* const* d_in, const int* in_sizes, int n_in,
                              void* d_out, int out_size, void* d_ws, size_t ws_size,
                              hipStream_t stream) {
    const float* x  = (const float*)d_in[0];
    const unsigned int* eidx = (const unsigned int*)d_in[1];
    const float* W1 = (const float*)d_in[2];
    const float* b1 = (const float*)d_in[3];
    const float* W2 = (const float*)d_in[4];
    const float* b2 = (const float*)d_in[5];
    const float* Wc = (const float*)d_in[6];
    const float* bc = (const float*)d_in[7];
    float* out = (float*)d_out;

    int N = in_sizes[0] / IN_D;
    int E = in_sizes[1] / 2;
    int nblkN = (N + 255) / 256;      // 391 for N=100k (<= 512 for scanB)
    int nbuk  = (N + 511) >> 9;       // 196 buckets of 512 nodes

    char* p = (char*)d_ws;
    int*   src     = (int*)p;    p += (size_t)E * 4;
    int*   dst     = (int*)p;    p += (size_t)E * 4;
    int*   deg     = (int*)p;    p += (size_t)N * 4;
    int*   part    = (int*)p;    p += (size_t)N * 4;
    int*   blksum  = (int*)p;    p += 512 * 4;
    int*   bcur    = (int*)p;    p += 256 * 4;
    int*   row_ptr = (int*)p;    p += (size_t)(N + 1) * 4;
    int*   csr_src = (int*)p;    p += (size_t)E * 4;
    float* dinv    = (float*)p;  p += (size_t)N * 4;
    float* s0      = (float*)p;  p += (size_t)N * 4;
    float* s1      = (float*)p;  p += (size_t)N * 4;
    p += 15; p = (char*)((size_t)p & ~(size_t)15);
    int2*  pairs   = (int2*)p;   p += (size_t)E * 8;   // dead after k_place2
    float* p0p     = (float*)pairs;                    // alias: 4N floats
    float* p1p     = p0p + 4 * (size_t)N;
    __half* xs    = (__half*)p;  p += (size_t)N * 64 * 2;
    __half* aggh  = (__half*)p;  p += (size_t)N * 64 * 2;
    __half* ts    = (__half*)p;  p += (size_t)N * 64 * 2;
    __half* w1f   = (__half*)p;  p += 8192 * 2;
    __half* w2f   = (__half*)p;  p += 8192 * 2;

    hipMemsetAsync(deg, 0, (size_t)N * 4, stream);

    // CSR build: decode+histogram, scan, 2-phase bucketed place
    k_decode<<<(E + 255) / 256, 256, 0, stream>>>(eidx, E, src, dst, deg);
    k_wconv<<<8, 256, 0, stream>>>(W1, W2, w1f, w2f);
    k_scanA<<<nblkN, 256, 0, stream>>>(deg, part, blksum, N);
    k_scanB<<<1, 512, 0, stream>>>(blksum, nblkN);
    k_scanC<<<nblkN, 256, 0, stream>>>(deg, part, blksum, row_ptr, bcur, dinv, N, E);
    k_part<<<(E + CHUNK - 1) / CHUNK, 256, 0, stream>>>(src, dst, bcur, pairs, E);
    k_place2<<<nbuk, 256, 0, stream>>>(pairs, row_ptr, csr_src, N);

    // Pre-scaled fp16 features in 4 column panels; layer-1 gather (XCD-affine)
    k_xconv<<<(N * 32 + 255) / 256, 256, 0, stream>>>(x, dinv, xs, N);
    k_gather1<<<((N + 7) / 8) * 4, 256, 0, stream>>>(xs, dinv, row_ptr, csr_src, aggh, N);

    // MFMA fused MLP (row-major agg in, panel-layout ts out)
    k_mlp_mfma<<<(N + 63) / 64, 256, 0, stream>>>(aggh, w1f, w2f, b1, dinv, ts, N);

    // Layer-2 panel gather fused with b2/relu/Wc partial scores, then panel-sum
    k_gather2<<<((N + 7) / 8) * 4, 256, 0, stream>>>(ts, dinv, row_ptr, csr_src,
                                                     b2, Wc, p0p, p1p, N);
    k_sfin<<<(N + 255) / 256, 256, 0, stream>>>(p0p, p1p, s0, s1, N);

    // Per-edge sigmoid from per-node partial scores
    k_edge<<<(E + 255) / 256, 256, 0, stream>>>(src, dst, s0, s1, bc, out, E);
}

// Round 6
// 280.923 us; speedup vs baseline: 1.2462x; 1.2462x over previous
//
#include <hip/hip_runtime.h>
#include <hip/hip_fp16.h>
#include <math.h>

#define IN_D 64
#define HID_D 128
#define OUT_D 64

typedef _Float16 half8 __attribute__((ext_vector_type(8)));
typedef float f32x4 __attribute__((ext_vector_type(4)));

// ---------------------------------------------------------------------------
// Decode edge_index (robust to int32 or int64 storage) + int in-degree histogram
__global__ void k_decode(const unsigned int* __restrict__ raw, int E,
                         int* __restrict__ src, int* __restrict__ dst,
                         int* __restrict__ deg) {
    __shared__ int is64;
    if (threadIdx.x == 0) {
        int f = 1;
        for (int i = 1; i < 64; i += 2) f &= (raw[i] == 0u);
        is64 = f;
    }
    __syncthreads();
    int e = blockIdx.x * blockDim.x + threadIdx.x;
    if (e >= E) return;
    int s, d;
    if (is64) {
        s = (int)raw[2 * (size_t)e];
        d = (int)raw[2 * ((size_t)E + e)];
    } else {
        s = (int)raw[e];
        d = (int)raw[E + e];
    }
    src[e] = s;
    dst[e] = d;
    atomicAdd(&deg[d], 1);
}

// ---------------------------------------------------------------------------
// Exclusive scan of deg -> row_ptr
__global__ void k_scanA(const int* __restrict__ deg, int* __restrict__ part,
                        int* __restrict__ blksum, int N) {
    int i = blockIdx.x * 256 + threadIdx.x;
    int v = (i < N) ? deg[i] : 0;
    int lane = threadIdx.x & 63, w = threadIdx.x >> 6;
    for (int off = 1; off < 64; off <<= 1) {
        int n = __shfl_up(v, off);
        if (lane >= off) v += n;
    }
    __shared__ int wsum[4];
    if (lane == 63) wsum[w] = v;
    __syncthreads();
    for (int k = 0; k < w; ++k) v += wsum[k];
    if (i < N) part[i] = v;
    if (threadIdx.x == 255) blksum[blockIdx.x] = v;
}

__global__ void k_scanB(int* __restrict__ blksum, int nb) {
    int t = threadIdx.x;  // 512 threads, nb <= 512
    int v = (t < nb) ? blksum[t] : 0;
    int orig = v;
    int lane = t & 63, w = t >> 6;
    for (int off = 1; off < 64; off <<= 1) {
        int n = __shfl_up(v, off);
        if (lane >= off) v += n;
    }
    __shared__ int wsum[8];
    if (lane == 63) wsum[w] = v;
    __syncthreads();
    for (int k = 0; k < w; ++k) v += wsum[k];
    if (t < nb) blksum[t] = v - orig;
}

// row_ptr, dinv, and per-bucket base cursors (bucket = dst>>9)
__global__ void k_scanC(const int* __restrict__ deg, const int* __restrict__ part,
                        const int* __restrict__ blksum, int* __restrict__ row_ptr,
                        int* __restrict__ bcur, float* __restrict__ dinv,
                        int N, int E) {
    int i = blockIdx.x * 256 + threadIdx.x;
    if (i == 0) row_ptr[N] = E;
    if (i >= N) return;
    int start = part[i] - deg[i] + blksum[blockIdx.x];
    row_ptr[i] = start;
    if ((i & 511) == 0) bcur[i >> 9] = start;
    dinv[i] = rsqrtf((float)deg[i] + 1.0f);  // +1 = self loop
}

// ---------------------------------------------------------------------------
// Phase A: partition edges into coarse dst-buckets (512 nodes each).
#define CHUNK 2048
__global__ __launch_bounds__(256) void k_part(const int* __restrict__ src,
                                              const int* __restrict__ dst,
                                              int* __restrict__ bcur,
                                              int2* __restrict__ pairs, int E) {
    __shared__ int hist[256];
    __shared__ int base[256];
    __shared__ int cnt[256];
    for (int i = threadIdx.x; i < 256; i += 256) { hist[i] = 0; cnt[i] = 0; }
    __syncthreads();
    int e0 = blockIdx.x * CHUNK;
    int s[8], d[8], b[8];
#pragma unroll
    for (int i = 0; i < 8; ++i) {
        int e = e0 + threadIdx.x + i * 256;
        if (e < E) {
            s[i] = src[e]; d[i] = dst[e]; b[i] = d[i] >> 9;
            atomicAdd(&hist[b[i]], 1);
        } else b[i] = -1;
    }
    __syncthreads();
    if (hist[threadIdx.x] > 0)
        base[threadIdx.x] = atomicAdd(&bcur[threadIdx.x], hist[threadIdx.x]);
    __syncthreads();
#pragma unroll
    for (int i = 0; i < 8; ++i) {
        if (b[i] >= 0) {
            int pos = base[b[i]] + atomicAdd(&cnt[b[i]], 1);
            pairs[pos] = make_int2(s[i], d[i]);
        }
    }
}

// Phase B: one block per bucket; LDS cursors; confined writes.
__global__ __launch_bounds__(256) void k_place2(const int2* __restrict__ pairs,
                                                const int* __restrict__ row_ptr,
                                                int* __restrict__ csr_src, int N) {
    __shared__ int cur[512];
    int b = blockIdx.x;
    int n0 = b << 9;
    int n1 = n0 + 512; if (n1 > N) n1 = N;
    for (int j = threadIdx.x; j < n1 - n0; j += 256) cur[j] = row_ptr[n0 + j];
    __syncthreads();
    int beg = row_ptr[n0], end = row_ptr[n1];
    for (int i = beg + threadIdx.x; i < end; i += 256) {
        int2 r = pairs[i];
        int pos = atomicAdd(&cur[r.y - n0], 1);
        csr_src[pos] = r.x;
    }
}

// ---------------------------------------------------------------------------
// xs[i,:] = fp16( dinv[i] * x[i,:] ), row-major
__global__ void k_xconv(const float* __restrict__ x, const float* __restrict__ dinv,
                        __half* __restrict__ xs, int N) {
    int idx = blockIdx.x * blockDim.x + threadIdx.x;
    if (idx >= N * 32) return;
    int i = idx >> 5, c = (idx & 31) * 2;
    float di = dinv[i];
    float2 v = *(const float2*)&x[(size_t)i * 64 + c];
    *(__half2*)&xs[(size_t)i * 64 + c] = __floats2half2_rn(v.x * di, v.y * di);
}

// ---------------------------------------------------------------------------
// Pre-pack W1 (A-operand layout) and W2 (B-operand layout) into MFMA fragment order.
__global__ void k_wconv(const float* __restrict__ W1, const float* __restrict__ W2,
                        __half* __restrict__ w1f, __half* __restrict__ w2f) {
    int t = blockIdx.x * 256 + threadIdx.x;  // 0..2047
    if (t >= 2048) return;
    int which = t >> 10;
    int fl = t & 1023;
    int f = fl >> 6, l = fl & 63;
    int q = l >> 4, n16 = l & 15;
    if (which == 0) {
        int nt = f >> 1, kc = f & 1;
        int n = nt * 16 + n16;
        int k0 = kc * 32 + q * 8;
        for (int j = 0; j < 8; ++j)
            w1f[(size_t)fl * 8 + j] = __float2half(W1[(k0 + j) * 128 + n]);
    } else {
        int nt = f >> 2, kc = f & 3;
        int n = nt * 16 + n16;
        int k0 = kc * 32 + q * 8;
        for (int j = 0; j < 8; ++j)
            w2f[(size_t)fl * 8 + j] = __float2half(W2[(k0 + j) * 64 + n]);
    }
}

// ---------------------------------------------------------------------------
// Layer-1 gather: wave = 1 node, 8 neighbor-slots x 8 col-segments, 16 B loads.
// agg[node,:] = fp16( dinv * (self + sum nbrs) )      (xs pre-scaled by dinv[src])
__global__ void k_gather1(const __half* __restrict__ xs, const float* __restrict__ dinv,
                          const int* __restrict__ row_ptr, const int* __restrict__ csr,
                          __half* __restrict__ agg, int N) {
    int node = blockIdx.x * 4 + (threadIdx.x >> 6);
    if (node >= N) return;
    int l = threadIdx.x & 63;
    int slot = l >> 3, seg = l & 7;
    int beg = row_ptr[node], end = row_ptr[node + 1];
    float acc[8];
#pragma unroll
    for (int j = 0; j < 8; ++j) acc[j] = 0.f;
    int k = beg + slot;
    for (; k + 8 < end; k += 16) {
        int s0 = csr[k], s1 = csr[k + 8];
        half8 h0 = *(const half8*)&xs[(size_t)s0 * 64 + seg * 8];
        half8 h1 = *(const half8*)&xs[(size_t)s1 * 64 + seg * 8];
#pragma unroll
        for (int j = 0; j < 8; ++j) acc[j] += (float)h0[j] + (float)h1[j];
    }
    if (k < end) {
        int s0 = csr[k];
        half8 h0 = *(const half8*)&xs[(size_t)s0 * 64 + seg * 8];
#pragma unroll
        for (int j = 0; j < 8; ++j) acc[j] += (float)h0[j];
    }
#pragma unroll
    for (int j = 0; j < 8; ++j) {
        acc[j] += __shfl_xor(acc[j], 8);
        acc[j] += __shfl_xor(acc[j], 16);
        acc[j] += __shfl_xor(acc[j], 32);
    }
    if (slot == 0) {
        half8 hs = *(const half8*)&xs[(size_t)node * 64 + seg * 8];
        float di = dinv[node];
        half8 o;
#pragma unroll
        for (int j = 0; j < 8; ++j) o[j] = (_Float16)((acc[j] + (float)hs[j]) * di);
        *(half8*)&agg[(size_t)node * 64 + seg * 8] = o;
    }
}

// Layer-2 gather fused with +b2, relu, and both Wc dot products.
__global__ void k_gather2(const __half* __restrict__ ts, const float* __restrict__ dinv,
                          const int* __restrict__ row_ptr, const int* __restrict__ csr,
                          const float* __restrict__ b2, const float* __restrict__ Wc,
                          float* __restrict__ s0o, float* __restrict__ s1o, int N) {
    int node = blockIdx.x * 4 + (threadIdx.x >> 6);
    if (node >= N) return;
    int l = threadIdx.x & 63;
    int slot = l >> 3, seg = l & 7;
    int beg = row_ptr[node], end = row_ptr[node + 1];
    float acc[8];
#pragma unroll
    for (int j = 0; j < 8; ++j) acc[j] = 0.f;
    int k = beg + slot;
    for (; k + 8 < end; k += 16) {
        int s0 = csr[k], s1 = csr[k + 8];
        half8 h0 = *(const half8*)&ts[(size_t)s0 * 64 + seg * 8];
        half8 h1 = *(const half8*)&ts[(size_t)s1 * 64 + seg * 8];
#pragma unroll
        for (int j = 0; j < 8; ++j) acc[j] += (float)h0[j] + (float)h1[j];
    }
    if (k < end) {
        int s0 = csr[k];
        half8 h0 = *(const half8*)&ts[(size_t)s0 * 64 + seg * 8];
#pragma unroll
        for (int j = 0; j < 8; ++j) acc[j] += (float)h0[j];
    }
#pragma unroll
    for (int j = 0; j < 8; ++j) {
        acc[j] += __shfl_xor(acc[j], 8);
        acc[j] += __shfl_xor(acc[j], 16);
        acc[j] += __shfl_xor(acc[j], 32);
    }
    if (slot == 0) {
        half8 hs = *(const half8*)&ts[(size_t)node * 64 + seg * 8];
        float di = dinv[node];
        float4 b2a = *(const float4*)&b2[seg * 8];
        float4 b2b = *(const float4*)&b2[seg * 8 + 4];
        float4 w0a = *(const float4*)&Wc[seg * 8];
        float4 w0b = *(const float4*)&Wc[seg * 8 + 4];
        float4 w1a = *(const float4*)&Wc[64 + seg * 8];
        float4 w1b = *(const float4*)&Wc[64 + seg * 8 + 4];
        float bb[8] = {b2a.x, b2a.y, b2a.z, b2a.w, b2b.x, b2b.y, b2b.z, b2b.w};
        float w0[8] = {w0a.x, w0a.y, w0a.z, w0a.w, w0b.x, w0b.y, w0b.z, w0b.w};
        float w1[8] = {w1a.x, w1a.y, w1a.z, w1a.w, w1b.x, w1b.y, w1b.z, w1b.w};
        float p0 = 0.f, p1 = 0.f;
#pragma unroll
        for (int j = 0; j < 8; ++j) {
            float v = fmaxf((acc[j] + (float)hs[j]) * di + bb[j], 0.f);
            p0 = fmaf(v, w0[j], p0);
            p1 = fmaf(v, w1[j], p1);
        }
        p0 += __shfl_xor(p0, 1); p1 += __shfl_xor(p1, 1);
        p0 += __shfl_xor(p0, 2); p1 += __shfl_xor(p1, 2);
        p0 += __shfl_xor(p0, 4); p1 += __shfl_xor(p1, 4);
        if (seg == 0) { s0o[node] = p0; s1o[node] = p1; }
    }
}

// ---------------------------------------------------------------------------
// MFMA fused MLP: ts = fp16( dinv * ( relu(agg @ W1 + b1) @ W2 ) ), row-major out
__global__ __launch_bounds__(256) void k_mlp_mfma(const __half* __restrict__ agg_h,
                                                  const __half* __restrict__ w1f,
                                                  const __half* __restrict__ w2f,
                                                  const float* __restrict__ b1,
                                                  const float* __restrict__ dinv,
                                                  __half* __restrict__ ts, int N) {
    __shared__ __align__(16) __half w1l[8192];
    __shared__ __align__(16) __half w2l[8192];
    {
        const float4* sA = (const float4*)w1f;
        const float4* sB = (const float4*)w2f;
        float4* dA = (float4*)w1l;
        float4* dB = (float4*)w2l;
        for (int i = threadIdx.x; i < 1024; i += 256) { dA[i] = sA[i]; dB[i] = sB[i]; }
    }
    __syncthreads();

    int wv = threadIdx.x >> 6, l = threadIdx.x & 63;
    int m0 = blockIdx.x * 64 + wv * 16;
    if (m0 >= N) return;
    int q = l >> 4, ml = l & 15;
    int rowA = m0 + ml; if (rowA >= N) rowA = N - 1;

    half8 bfr0 = *(const half8*)&agg_h[(size_t)rowA * 64 + q * 8];
    half8 bfr1 = *(const half8*)&agg_h[(size_t)rowA * 64 + 32 + q * 8];

    int pk[8][2];
#pragma unroll
    for (int nt = 0; nt < 8; ++nt) {
        float4 bb = *(const float4*)&b1[nt * 16 + q * 4];
        f32x4 cacc; cacc[0] = bb.x; cacc[1] = bb.y; cacc[2] = bb.z; cacc[3] = bb.w;
        half8 a0 = *(const half8*)&w1l[(nt * 2 + 0) * 512 + l * 8];
        cacc = __builtin_amdgcn_mfma_f32_16x16x32_f16(a0, bfr0, cacc, 0, 0, 0);
        half8 a1 = *(const half8*)&w1l[(nt * 2 + 1) * 512 + l * 8];
        cacc = __builtin_amdgcn_mfma_f32_16x16x32_f16(a1, bfr1, cacc, 0, 0, 0);
        union { __half2 h; int i; } u0, u1;
        u0.h = __floats2half2_rn(fmaxf(cacc[0], 0.f), fmaxf(cacc[1], 0.f));
        u1.h = __floats2half2_rn(fmaxf(cacc[2], 0.f), fmaxf(cacc[3], 0.f));
        pk[nt][0] = u0.i;
        pk[nt][1] = u1.i;
    }

    int src0 = ml + 16 * ((2 * q) & 3);
    int src1 = ml + 16 * ((2 * q + 1) & 3);
    bool hi = (q >= 2);
    half8 afr[4];
#pragma unroll
    for (int kc = 0; kc < 4; ++kc) {
        int t0 = 2 * kc, t1 = 2 * kc + 1;
        int d0a = __shfl(pk[t0][0], src0), d0b = __shfl(pk[t1][0], src0);
        int d1a = __shfl(pk[t0][1], src0), d1b = __shfl(pk[t1][1], src0);
        int d2a = __shfl(pk[t0][0], src1), d2b = __shfl(pk[t1][0], src1);
        int d3a = __shfl(pk[t0][1], src1), d3b = __shfl(pk[t1][1], src1);
        union { int d[4]; half8 h; } u;
        u.d[0] = hi ? d0b : d0a;
        u.d[1] = hi ? d1b : d1a;
        u.d[2] = hi ? d2b : d2a;
        u.d[3] = hi ? d3b : d3a;
        afr[kc] = u.h;
    }

    float dl = dinv[rowA];
    float dv[4];
#pragma unroll
    for (int r = 0; r < 4; ++r) dv[r] = __shfl(dl, q * 4 + r);

#pragma unroll
    for (int nt2 = 0; nt2 < 4; ++nt2) {
        f32x4 cacc; cacc[0] = 0.f; cacc[1] = 0.f; cacc[2] = 0.f; cacc[3] = 0.f;
#pragma unroll
        for (int kc = 0; kc < 4; ++kc) {
            half8 b = *(const half8*)&w2l[(nt2 * 4 + kc) * 512 + l * 8];
            cacc = __builtin_amdgcn_mfma_f32_16x16x32_f16(afr[kc], b, cacc, 0, 0, 0);
        }
#pragma unroll
        for (int r = 0; r < 4; ++r) {
            int node = m0 + q * 4 + r;
            if (node < N)
                ts[(size_t)node * 64 + nt2 * 16 + ml] = __float2half(cacc[r] * dv[r]);
        }
    }
}

__global__ void k_edge(const int* __restrict__ src, const int* __restrict__ dst,
                       const float* __restrict__ s0, const float* __restrict__ s1,
                       const float* __restrict__ bc, float* __restrict__ out, int E) {
    int e = blockIdx.x * blockDim.x + threadIdx.x;
    if (e >= E) return;
    float z = s0[src[e]] + s1[dst[e]] + bc[0];
    out[e] = 1.0f / (1.0f + expf(-z));
}

// ---------------------------------------------------------------------------
extern "C" void kernel_launch(void* const* d_in, const int* in_sizes, int n_in,
                              void* d_out, int out_size, void* d_ws, size_t ws_size,
                              hipStream_t stream) {
    const float* x  = (const float*)d_in[0];
    const unsigned int* eidx = (const unsigned int*)d_in[1];
    const float* W1 = (const float*)d_in[2];
    const float* b1 = (const float*)d_in[3];
    const float* W2 = (const float*)d_in[4];
    const float* b2 = (const float*)d_in[5];
    const float* Wc = (const float*)d_in[6];
    const float* bc = (const float*)d_in[7];
    float* out = (float*)d_out;

    int N = in_sizes[0] / IN_D;
    int E = in_sizes[1] / 2;
    int nblkN = (N + 255) / 256;      // 391 for N=100k (<= 512 for scanB)
    int nbuk  = (N + 511) >> 9;       // 196 buckets of 512 nodes (<= 256)

    char* p = (char*)d_ws;
    int*   src     = (int*)p;    p += (size_t)E * 4;
    int*   dst     = (int*)p;    p += (size_t)E * 4;
    int*   deg     = (int*)p;    p += (size_t)N * 4;
    int*   part    = (int*)p;    p += (size_t)N * 4;
    int*   blksum  = (int*)p;    p += 512 * 4;
    int*   bcur    = (int*)p;    p += 256 * 4;
    int*   row_ptr = (int*)p;    p += (size_t)(N + 1) * 4;
    int*   csr_src = (int*)p;    p += (size_t)E * 4;
    float* dinv    = (float*)p;  p += (size_t)N * 4;
    float* s0      = (float*)p;  p += (size_t)N * 4;
    float* s1      = (float*)p;  p += (size_t)N * 4;
    p += 15; p = (char*)((size_t)p & ~(size_t)15);
    int2*  pairs   = (int2*)p;   p += (size_t)E * 8;   // dead after k_place2
    __half* xs    = (__half*)p;  p += (size_t)N * 64 * 2;
    __half* aggh  = (__half*)p;  p += (size_t)N * 64 * 2;
    __half* ts    = (__half*)p;  p += (size_t)N * 64 * 2;
    __half* w1f   = (__half*)p;  p += 8192 * 2;
    __half* w2f   = (__half*)p;  p += 8192 * 2;

    hipMemsetAsync(deg, 0, (size_t)N * 4, stream);

    // CSR build: decode+histogram, scan, 2-phase bucketed place
    k_decode<<<(E + 255) / 256, 256, 0, stream>>>(eidx, E, src, dst, deg);
    k_wconv<<<8, 256, 0, stream>>>(W1, W2, w1f, w2f);
    k_scanA<<<nblkN, 256, 0, stream>>>(deg, part, blksum, N);
    k_scanB<<<1, 512, 0, stream>>>(blksum, nblkN);
    k_scanC<<<nblkN, 256, 0, stream>>>(deg, part, blksum, row_ptr, bcur, dinv, N, E);
    k_part<<<(E + CHUNK - 1) / CHUNK, 256, 0, stream>>>(src, dst, bcur, pairs, E);
    k_place2<<<nbuk, 256, 0, stream>>>(pairs, row_ptr, csr_src, N);

    // Pre-scaled fp16 features (row-major); layer-1 gather
    k_xconv<<<(N * 32 + 255) / 256, 256, 0, stream>>>(x, dinv, xs, N);
    k_gather1<<<(N + 3) / 4, 256, 0, stream>>>(xs, dinv, row_ptr, csr_src, aggh, N);

    // MFMA fused MLP
    k_mlp_mfma<<<(N + 63) / 64, 256, 0, stream>>>(aggh, w1f, w2f, b1, dinv, ts, N);

    // Layer-2 gather fused with b2/relu/Wc scores
    k_gather2<<<(N + 3) / 4, 256, 0, stream>>>(ts, dinv, row_ptr, csr_src,
                                               b2, Wc, s0, s1, N);

    // Per-edge sigmoid from per-node partial scores
    k_edge<<<(E + 255) / 256, 256, 0, stream>>>(src, dst, s0, s1, bc, out, E);
}